// Round 2
// baseline (784.524 us; speedup 1.0000x reference)
//
#include <hip/hip_runtime.h>
#include <cstdint>
#include <cstddef>

#define N_INS    16384
#define INS_DIM  2048
#define N_CLS    81
#define BANK     10
#define LIST_CAP 1024

// ---------------------------------------------------------------------------
// Kernel 1: per-class mean over bank + ||mean||^2
// ---------------------------------------------------------------------------
__global__ __launch_bounds__(256)
void prep_kernel(const float* __restrict__ memory,
                 float* __restrict__ mean_out,   // [81][2048]
                 float* __restrict__ base_out)   // [81]
{
    const int c = blockIdx.x;
    const int t = threadIdx.x;
    double nrm = 0.0;
    #pragma unroll
    for (int rep = 0; rep < 2; ++rep) {
        const int d4 = (t + rep * 256) * 4;
        float sx = 0.f, sy = 0.f, sz = 0.f, sw = 0.f;
        #pragma unroll
        for (int b = 0; b < BANK; ++b) {
            const float4 v = *(const float4*)(memory + ((size_t)(c * BANK + b)) * INS_DIM + d4);
            sx += v.x; sy += v.y; sz += v.z; sw += v.w;
        }
        sx /= 10.0f; sy /= 10.0f; sz /= 10.0f; sw /= 10.0f;
        *(float4*)(mean_out + (size_t)c * INS_DIM + d4) = make_float4(sx, sy, sz, sw);
        nrm += (double)sx * sx + (double)sy * sy + (double)sz * sz + (double)sw * sw;
    }
    #pragma unroll
    for (int off = 32; off >= 1; off >>= 1) nrm += __shfl_xor(nrm, off, 64);
    __shared__ double sred[4];
    const int w = t >> 6, lane = t & 63;
    if (lane == 0) sred[w] = nrm;
    __syncthreads();
    if (t == 0) base_out[c] = (float)(sred[0] + sred[1] + sred[2] + sred[3]);
}

// ---------------------------------------------------------------------------
// Kernel 2: classification. Block = 128 threads, tile 64 inst x 96 cls.
// Thread map: ig = t&7 (8 instances each), cg = t>>3 (6 classes each).
// A staged k-major in LDS so the A fragment is 2x ds_read_b128.
// ---------------------------------------------------------------------------
#define CBK   64
#define SA_ST 68     // 64 + 4 pad (k-major row stride, floats)
#define SB_ST 100    // 96 + 4 pad

__global__ __launch_bounds__(128)
void classify_kernel(const float* __restrict__ instances,
                     const int*   __restrict__ labels,
                     const float* __restrict__ mean_in,   // [81][2048]
                     const float* __restrict__ base_in,   // [81]
                     float* __restrict__ cls_out,         // [16384]
                     float* __restrict__ acc_out)         // [1]
{
    __shared__ float  sA[CBK * SA_ST];   // [k][inst]   17.4 KB
    __shared__ float  sB[CBK * SB_ST];   // [k][cls]    25.6 KB
    __shared__ double redS[64 * 16];
    __shared__ int    redC[64 * 16];

    const int t  = threadIdx.x;   // 0..127
    const int ig = t & 7;         // 8 groups x 8 instances
    const int cg = t >> 3;        // 16 groups x 6 classes
    const int i0 = blockIdx.x * 64;

    float  cacc[8][6];
    double dacc[8][6];
    #pragma unroll
    for (int q = 0; q < 8; ++q)
        #pragma unroll
        for (int j = 0; j < 6; ++j) dacc[q][j] = 0.0;

    for (int k0 = 0; k0 < INS_DIM; k0 += CBK) {
        // stage A (64 rows x 64 k) -> k-major sA[k][i]
        #pragma unroll
        for (int it = 0; it < 8; ++it) {
            const int r = (t >> 3) + 16 * (it & 3);
            const int q = (t & 7) + 8 * (it >> 2);
            const float4 v = *(const float4*)(instances + (size_t)(i0 + r) * INS_DIM + k0 + q * 4);
            sA[(q * 4 + 0) * SA_ST + r] = v.x;
            sA[(q * 4 + 1) * SA_ST + r] = v.y;
            sA[(q * 4 + 2) * SA_ST + r] = v.z;
            sA[(q * 4 + 3) * SA_ST + r] = v.w;
        }
        // stage B (96 cls x 64 k) -> k-major sB[k][c]; pad classes duplicate c=80
        #pragma unroll
        for (int it = 0; it < 12; ++it) {
            const int u = t + 128 * it;
            const int c = u >> 4, q = u & 15;
            const int cc = (c < N_CLS) ? c : (N_CLS - 1);
            const float4 v = *(const float4*)(mean_in + (size_t)cc * INS_DIM + k0 + q * 4);
            sB[(q * 4 + 0) * SB_ST + c] = v.x;
            sB[(q * 4 + 1) * SB_ST + c] = v.y;
            sB[(q * 4 + 2) * SB_ST + c] = v.z;
            sB[(q * 4 + 3) * SB_ST + c] = v.w;
        }
        __syncthreads();

        #pragma unroll
        for (int q = 0; q < 8; ++q)
            #pragma unroll
            for (int j = 0; j < 6; ++j) cacc[q][j] = 0.0f;

        #pragma unroll 4
        for (int k = 0; k < CBK; ++k) {
            const float4 a0 = *(const float4*)&sA[k * SA_ST + ig * 8];
            const float4 a1 = *(const float4*)&sA[k * SA_ST + ig * 8 + 4];
            const float* bp = &sB[k * SB_ST + cg * 6];
            const float2 b01 = *(const float2*)(bp);
            const float2 b23 = *(const float2*)(bp + 2);
            const float2 b45 = *(const float2*)(bp + 4);
            const float av[8] = { a0.x, a0.y, a0.z, a0.w, a1.x, a1.y, a1.z, a1.w };
            const float bv[6] = { b01.x, b01.y, b23.x, b23.y, b45.x, b45.y };
            #pragma unroll
            for (int q = 0; q < 8; ++q)
                #pragma unroll
                for (int j = 0; j < 6; ++j) cacc[q][j] = fmaf(av[q], bv[j], cacc[q][j]);
        }
        #pragma unroll
        for (int q = 0; q < 8; ++q)
            #pragma unroll
            for (int j = 0; j < 6; ++j) dacc[q][j] += (double)cacc[q][j];
        __syncthreads();
    }

    // per-thread argmin over this thread's classes (ascending -> first-min)
    float bvals[6];
    #pragma unroll
    for (int j = 0; j < 6; ++j) {
        const int c = cg * 6 + j;
        bvals[j] = (c < N_CLS) ? base_in[c] : 0.0f;
    }
    #pragma unroll
    for (int q = 0; q < 8; ++q) {
        double best = 1e300; int bestc = 0x7fffffff;
        #pragma unroll
        for (int j = 0; j < 6; ++j) {
            const int c = cg * 6 + j;
            if (c < N_CLS) {
                const double sc = (double)bvals[j] - 2.0 * dacc[q][j];
                if (sc < best) { best = sc; bestc = c; }
            }
        }
        const int row = ig * 8 + q;
        redS[row * 16 + cg] = best;
        redC[row * 16 + cg] = bestc;
    }
    __syncthreads();

    if (t < 64) {
        double best = redS[t * 16 + 0]; int bc = redC[t * 16 + 0];
        #pragma unroll
        for (int g = 1; g < 16; ++g) {
            const double v = redS[t * 16 + g];
            if (v < best) { best = v; bc = redC[t * 16 + g]; }
        }
        const int gi = i0 + t;
        cls_out[gi] = (float)bc;
        const bool ok = (bc == labels[gi]);
        const unsigned long long m = __ballot(ok ? 1 : 0);
        if (t == 0) atomicAdd(acc_out, (float)__popcll(m) * (1.0f / 16384.0f));
    }
}

// ---------------------------------------------------------------------------
// Kernel 3: sequential per-class memory update, DOT-FORM scores.
// argmax_s ||m_s - x||^2  ==  argmax_s (||m_s||^2 - 2 m_s.x).
// Slot norms maintained incrementally (wave 2 computes ||x||^2 each step).
// Block = 1 class, 512 threads; wave w owns slot w; waves 0,1 also own 8,9.
// ---------------------------------------------------------------------------
__global__ __launch_bounds__(512, 2)
void update_kernel(const float* __restrict__ instances,
                   const int*   __restrict__ labels,
                   const float* __restrict__ memory,
                   const int*   __restrict__ memory_pos,
                   float* __restrict__ mem_out,   // [81][10][2048]
                   float* __restrict__ pos_out)   // [81]
{
    __shared__ int    s_list[LIST_CAP];
    __shared__ int    s_wcnt[8];
    __shared__ int    s_cnt;
    __shared__ double s_score[2][BANK];
    __shared__ double s_xx[2];

    const int c = blockIdx.x;
    const int t = threadIdx.x;
    const int w = t >> 6, lane = t & 63;

    // Phase 1: ordered list of instances with label == c (stable compaction)
    if (t == 0) s_cnt = 0;
    __syncthreads();
    for (int base = 0; base < N_INS; base += 512) {
        const int idx = base + t;
        const bool match = (labels[idx] == c);
        const unsigned long long mb = __ballot(match ? 1 : 0);
        if (lane == 0) s_wcnt[w] = (int)__popcll(mb);
        __syncthreads();
        int off = s_cnt;
        for (int ww = 0; ww < w; ++ww) off += s_wcnt[ww];
        off += (int)__popcll(mb & ((1ull << lane) - 1ull));
        if (match && off < LIST_CAP) s_list[off] = idx;
        __syncthreads();
        if (t == 0) {
            int tot = 0;
            for (int ww = 0; ww < 8; ++ww) tot += s_wcnt[ww];
            s_cnt = min(s_cnt + tot, LIST_CAP);
        }
        __syncthreads();
    }
    const int cnt = s_cnt;

    // Phase 2: load bank into registers + initial slot norms
    const int s0 = w;
    const int s1 = (w < 2) ? (8 + w) : -1;
    float4 m0[8], m1[8];
    #pragma unroll
    for (int j = 0; j < 8; ++j)
        m0[j] = *(const float4*)(memory + ((size_t)(c * BANK + s0)) * INS_DIM + j * 256 + lane * 4);
    #pragma unroll
    for (int j = 0; j < 8; ++j) m1[j] = make_float4(0.f, 0.f, 0.f, 0.f);
    if (s1 >= 0) {
        #pragma unroll
        for (int j = 0; j < 8; ++j)
            m1[j] = *(const float4*)(memory + ((size_t)(c * BANK + s1)) * INS_DIM + j * 256 + lane * 4);
    }
    int p = memory_pos[c];

    double n0 = 0.0, n1 = 0.0;
    {
        #pragma unroll
        for (int h = 0; h < 2; ++h) {
            float ax = 0.f, ay = 0.f, az = 0.f, aw = 0.f;
            float bx = 0.f, by = 0.f, bz = 0.f, bw = 0.f;
            #pragma unroll
            for (int j = 4 * h; j < 4 * h + 4; ++j) {
                ax = fmaf(m0[j].x, m0[j].x, ax); ay = fmaf(m0[j].y, m0[j].y, ay);
                az = fmaf(m0[j].z, m0[j].z, az); aw = fmaf(m0[j].w, m0[j].w, aw);
                bx = fmaf(m1[j].x, m1[j].x, bx); by = fmaf(m1[j].y, m1[j].y, by);
                bz = fmaf(m1[j].z, m1[j].z, bz); bw = fmaf(m1[j].w, m1[j].w, bw);
            }
            n0 += (double)((ax + ay) + (az + aw));
            n1 += (double)((bx + by) + (bz + bw));
        }
        #pragma unroll
        for (int off = 32; off >= 1; off >>= 1) {
            n0 += __shfl_xor(n0, off, 64);
            n1 += __shfl_xor(n1, off, 64);
        }
    }

    // Phase 3: sequential scan, dot-form scores, prefetch double-buffer
    float4 xa[8], xb[8];
    #pragma unroll
    for (int j = 0; j < 8; ++j) { xa[j] = make_float4(0,0,0,0); xb[j] = make_float4(0,0,0,0); }
    if (cnt > 0) {
        const float* xp = instances + (size_t)s_list[0] * INS_DIM;
        #pragma unroll
        for (int j = 0; j < 8; ++j) xa[j] = *(const float4*)(xp + j * 256 + lane * 4);
    }

    auto stepf = [&](float4 (&xc)[8], float4 (&xn)[8], const int ii) {
        // prefetch next instance (in flight through reduce + barrier)
        const int nidx = s_list[(ii + 1 < cnt) ? (ii + 1) : ii];
        const float* np_ = instances + (size_t)nidx * INS_DIM;
        #pragma unroll
        for (int j = 0; j < 8; ++j) xn[j] = *(const float4*)(np_ + j * 256 + lane * 4);

        // dA = m0.x ; dB = m1.x (waves 0,1) or x.x (wave 2)
        double dA = 0.0, dB = 0.0;
        #pragma unroll
        for (int h = 0; h < 2; ++h) {
            float ax = 0.f, ay = 0.f, az = 0.f, aw = 0.f;
            float bx = 0.f, by = 0.f, bz = 0.f, bw = 0.f;
            #pragma unroll
            for (int j = 4 * h; j < 4 * h + 4; ++j) {
                ax = fmaf(m0[j].x, xc[j].x, ax); ay = fmaf(m0[j].y, xc[j].y, ay);
                az = fmaf(m0[j].z, xc[j].z, az); aw = fmaf(m0[j].w, xc[j].w, aw);
            }
            if (w < 2) {
                #pragma unroll
                for (int j = 4 * h; j < 4 * h + 4; ++j) {
                    bx = fmaf(m1[j].x, xc[j].x, bx); by = fmaf(m1[j].y, xc[j].y, by);
                    bz = fmaf(m1[j].z, xc[j].z, bz); bw = fmaf(m1[j].w, xc[j].w, bw);
                }
            } else if (w == 2) {
                #pragma unroll
                for (int j = 4 * h; j < 4 * h + 4; ++j) {
                    bx = fmaf(xc[j].x, xc[j].x, bx); by = fmaf(xc[j].y, xc[j].y, by);
                    bz = fmaf(xc[j].z, xc[j].z, bz); bw = fmaf(xc[j].w, xc[j].w, bw);
                }
            }
            dA += (double)((ax + ay) + (az + aw));
            dB += (double)((bx + by) + (bz + bw));
        }
        #pragma unroll
        for (int off = 32; off >= 1; off >>= 1) {
            dA += __shfl_xor(dA, off, 64);
            dB += __shfl_xor(dB, off, 64);
        }
        const int b = ii & 1;
        if (lane == 0) {
            s_score[b][s0] = n0 - 2.0 * dA;
            if (w < 2) s_score[b][8 + w] = n1 - 2.0 * dB;
            if (w == 2) s_xx[b] = dB;
        }
        __syncthreads();   // the only barrier per step (publish dbl-buffered)

        int widx;
        if (p < BANK) {
            widx = p;
        } else {
            double bv = s_score[b][0]; widx = 0;
            #pragma unroll
            for (int s = 1; s < BANK; ++s) {
                const double v = s_score[b][s];
                if (v > bv) { bv = v; widx = s; }   // strict > : first-max
            }
        }
        const double xxv = s_xx[b];
        if (widx == s0) {
            #pragma unroll
            for (int j = 0; j < 8; ++j) m0[j] = xc[j];
            n0 = xxv;
        }
        if (s1 >= 0 && widx == s1) {
            #pragma unroll
            for (int j = 0; j < 8; ++j) m1[j] = xc[j];
            n1 = xxv;
        }
        if (p < BANK) ++p;
    };

    int ii = 0;
    while (ii < cnt) {
        stepf(xa, xb, ii); ++ii;
        if (ii >= cnt) break;
        stepf(xb, xa, ii); ++ii;
    }

    // Phase 4: write final bank + pos
    #pragma unroll
    for (int j = 0; j < 8; ++j)
        *(float4*)(mem_out + ((size_t)(c * BANK + s0)) * INS_DIM + j * 256 + lane * 4) = m0[j];
    if (s1 >= 0) {
        #pragma unroll
        for (int j = 0; j < 8; ++j)
            *(float4*)(mem_out + ((size_t)(c * BANK + s1)) * INS_DIM + j * 256 + lane * 4) = m1[j];
    }
    if (t == 0) pos_out[c] = (float)p;
}

// ---------------------------------------------------------------------------
extern "C" void kernel_launch(void* const* d_in, const int* in_sizes, int n_in,
                              void* d_out, int out_size, void* d_ws, size_t ws_size,
                              hipStream_t stream)
{
    const float* instances = (const float*)d_in[0];
    const int*   labels    = (const int*)  d_in[1];
    const float* memory    = (const float*)d_in[2];
    const int*   mpos      = (const int*)  d_in[3];

    float* out      = (float*)d_out;
    float* cls_out  = out;                                      // [16384]
    float* acc_out  = out + N_INS;                              // [1]
    float* mem_out  = out + N_INS + 1;                          // [81*10*2048]
    float* pos_out  = mem_out + (size_t)N_CLS * BANK * INS_DIM; // [81]

    // scratch inside new_mem output region; update_kernel overwrites it last
    float* mean_scr = mem_out;                                  // [81*2048]
    float* base_scr = mem_out + (size_t)N_CLS * INS_DIM;        // [81]

    hipMemsetAsync(acc_out, 0, sizeof(float), stream);
    hipLaunchKernelGGL(prep_kernel, dim3(N_CLS), dim3(256), 0, stream,
                       memory, mean_scr, base_scr);
    hipLaunchKernelGGL(classify_kernel, dim3(N_INS / 64), dim3(128), 0, stream,
                       instances, labels, mean_scr, base_scr, cls_out, acc_out);
    hipLaunchKernelGGL(update_kernel, dim3(N_CLS), dim3(512), 0, stream,
                       instances, labels, memory, mpos, mem_out, pos_out);
}